// Round 1
// baseline (251.586 us; speedup 1.0000x reference)
//
#include <hip/hip_runtime.h>
#include <hip/hip_bf16.h>
#include <math.h>

#define NLINES 128
#define BUFLEN 48000
#define KLEN   96000
#define NBINS  64
#define TAP0   47935          // BUFLEN - NBINS - 1
#define CH     4              // m-chunks per line
#define MCH    (BUFLEN/CH)    // 12000
#define BG     8              // taps per group
#define NBG    (NBINS/BG)     // 8 groups

__device__ __forceinline__ float wave_reduce(float v){
  #pragma unroll
  for (int off = 32; off; off >>= 1) v += __shfl_down(v, off, 64);
  return v;
}

// Computes partial tap sums: tap[line][b] = sum_m buf[line][m] * h_line(n_b - m)
// h(x) = sin(pi x)/(K tan(pi x /K)) = (-1)^(s+1) sin(pi d)/K * cot(pi (s-d)/K)
__global__ __launch_bounds__(256) void frac_delay_taps(
    const float* __restrict__ buffer, const float* __restrict__ inputs,
    const float* __restrict__ delays, float* __restrict__ ws)
{
  const int blk   = blockIdx.x;
  const int line  = blk / (NBG * CH);
  const int rem   = blk % (NBG * CH);
  const int bg    = rem / CH;
  const int chunk = rem % CH;
  const int tid   = threadIdx.x;

  const float d = delays[line];
  // sin(pi*d) accurately: d = r + f, |f| <= 0.5 -> sin(pi d) = (-1)^r sin(pi f)
  const float r = rintf(d);
  const float f = d - r;
  float sp = __sinf(3.14159265358979323846f * f);
  if (((int)r) & 1) sp = -sp;
  const float scale = sp * (1.0f / (float)KLEN);

  const float inputv = inputs[line];
  const float* __restrict__ bufline = buffer + (size_t)line * BUFLEN;

  const float DLT = (float)(3.14159265358979323846 / (double)KLEN); // pi/K

  float acc[BG], acc2[BG], sb[BG];
  const int b0 = bg * BG;
  #pragma unroll
  for (int j = 0; j < BG; ++j){ acc[j] = 0.f; acc2[j] = 0.f; sb[j] = (float)(TAP0 + b0 + j); }

  const int m0   = chunk * MCH + tid;
  const int mend = chunk * MCH + MCH;
  for (int m = m0; m < mend; m += 256){
    // rolled buffer: buf[m] = buffer[m+1] for m < L-1, inputs for m = L-1
    const float v  = (m < BUFLEN - 1) ? bufline[m + 1] : inputv;
    const float mf = (float)m;
    #pragma unroll
    for (int j = 0; j < BG; ++j){
      const float xi = sb[j] - mf;          // exact (integers < 2^24)
      const float x  = xi - d;
      const float t  = x * DLT;
      const float cot = __fdividef(__cosf(t), __sinf(t));
      const bool hit = (x == 0.0f);          // exact integer delay hit (h = 1)
      acc[j]  += hit ? 0.0f : v * cot;
      acc2[j] += hit ? v : 0.0f;
    }
  }

  // sign (-1)^(s+1): s parity is constant per thread (m stride 256 even)
  __shared__ float red[4][BG];
  const int lane = tid & 63, wv = tid >> 6;
  const int p0 = (TAP0 + b0 - m0) & 1;
  #pragma unroll
  for (int j = 0; j < BG; ++j){
    const float sg = ((p0 + j) & 1) ? 1.0f : -1.0f;  // s odd -> +1
    float val = sg * scale * acc[j] + acc2[j];
    val = wave_reduce(val);
    if (lane == 0) red[wv][j] = val;
  }
  __syncthreads();
  if (tid < BG){
    const float s = red[0][tid] + red[1][tid] + red[2][tid] + red[3][tid];
    ws[(((size_t)line * NBG + bg) * CH + chunk) * BG + tid] = s;
  }
}

// out[line] = sum_b filt[line][b] * tap[line][b]
__global__ __launch_bounds__(64) void weight_reduce(
    const float* __restrict__ ws, const float* __restrict__ filt,
    float* __restrict__ out)
{
  const int line = blockIdx.x;
  const int tid  = threadIdx.x;          // 0..63 == tap index b
  const int bg = tid >> 3, bb = tid & 7;
  float s = 0.f;
  #pragma unroll
  for (int c = 0; c < CH; ++c)
    s += ws[(((size_t)line * NBG + bg) * CH + c) * BG + bb];
  float val = s * filt[line * NBINS + tid];
  val = wave_reduce(val);
  if (tid == 0) out[line] = val;
}

extern "C" void kernel_launch(void* const* d_in, const int* in_sizes, int n_in,
                              void* d_out, int out_size, void* d_ws, size_t ws_size,
                              hipStream_t stream)
{
  const float* buffer = (const float*)d_in[0];
  const float* inputs = (const float*)d_in[1];
  const float* delays = (const float*)d_in[2];
  const float* filt   = (const float*)d_in[3];
  float* out = (float*)d_out;
  float* ws  = (float*)d_ws;

  frac_delay_taps<<<NLINES * NBG * CH, 256, 0, stream>>>(buffer, inputs, delays, ws);
  weight_reduce<<<NLINES, 64, 0, stream>>>(ws, filt, out);
}

// Round 2
// 68.667 us; speedup vs baseline: 3.6639x; 3.6639x over previous
//
#include <hip/hip_runtime.h>
#include <hip/hip_bf16.h>
#include <math.h>

#define NLINES 128
#define BUFLEN 48000
#define KLEN   96000
#define NBINS  64
#define TAP0   47935          // BUFLEN - NBINS - 1
#define CH     4              // m-chunks per line
#define MCH    (BUFLEN/CH)    // 12000
#define BG     16             // taps per group
#define NBG    (NBINS/BG)     // 4 groups

#define DLT_D  3.2724923474893679e-05   // pi/K (double)
#define INV2K  ((float)(0.5/ (double)KLEN))  // revolutions per unit x

__device__ __forceinline__ float wave_reduce(float v){
  #pragma unroll
  for (int off = 32; off; off >>= 1) v += __shfl_down(v, off, 64);
  return v;
}

// tap[line][b] = sum_m buf[line][m] * h_line(n_b - m)
// h(x) = sin(pi x)/(K tan(pi x/K)) = (-1)^(s+1) sin(pi d)/K * cot(pi (s-d)/K)
// Fast path: cot(t0 + j*dlt) = (c - s*Tj)/(s + c*Tj), Tj = tan(j*dlt) const,
// with one batch-inverted reciprocal for all 16 denominators (scaled x32).
__global__ __launch_bounds__(256) void frac_delay_taps(
    const float* __restrict__ buffer, const float* __restrict__ inputs,
    const float* __restrict__ delays, float* __restrict__ ws)
{
  const int blk   = blockIdx.x;
  const int line  = blk / (NBG * CH);
  const int rem   = blk % (NBG * CH);
  const int bg    = rem / CH;
  const int chunk = rem % CH;
  const int tid   = threadIdx.x;

  const float d = delays[line];
  // sin(pi*d): d = r + f, |f| <= 0.5 -> sin(pi d) = (-1)^r sin(pi f)
  const float r = rintf(d);
  const float f = d - r;
  float sp = __builtin_amdgcn_sinf(0.5f * f);     // sin(pi*f)
  if (((int)r) & 1) sp = -sp;
  const float scaleF = sp * (32.0f / (float)KLEN); // x32 undoes denom scaling

  const float inputv = inputs[line];
  const float* __restrict__ bufline = buffer + (size_t)line * BUFLEN;

  const int   b0  = bg * BG;
  const float n0f = (float)(TAP0 + b0);

  float acc[BG];
  #pragma unroll
  for (int j = 0; j < BG; ++j) acc[j] = 0.f;
  float hitv = 0.f; int hitj = -1;   // at most one exact hit per thread

  const int m0   = chunk * MCH + tid;
  const int mend = chunk * MCH + MCH;
  for (int m = m0; m < mend; m += 256){
    // rolled buffer: buf[m] = buffer[m+1] for m < L-1, inputs for m = L-1
    const float v  = (m < BUFLEN - 1) ? bufline[m + 1] : inputv;
    const float mf = (float)m;
    const float x0 = (n0f - mf) - d;     // exact int diff, then small-sub

    if (fabsf(x0 + 7.5f) >= 32.0f) {
      // ---- fast path: min_j |x0+j| >= 24 ----
      const float tr  = x0 * INV2K;
      const float s   = __builtin_amdgcn_sinf(tr);   // sin(pi*x0/K)
      const float c   = __builtin_amdgcn_cosf(tr);
      const float vc  = v * c;
      const float vs  = v * s;
      const float s32 = 32.0f * s;
      float D[BG], P[BG];
      D[0] = s32; P[0] = s32;
      #pragma unroll
      for (int j = 1; j < BG; ++j){
        const float STj = (float)(32.0 * ((double)j * DLT_D)); // 32*tan(j*dlt)
        D[j] = fmaf(c, STj, s32);
        P[j] = P[j-1] * D[j];
      }
      float inv = __builtin_amdgcn_rcpf(P[BG-1]);
      #pragma unroll
      for (int j = BG-1; j >= 1; --j){
        const float Tj = (float)((double)j * DLT_D);           // tan(j*dlt)
        const float Ij = inv * P[j-1];                         // 1/(32*Dj)
        acc[j] = fmaf(fmaf(vs, -Tj, vc), Ij, acc[j]);          // += v*cot_j/32
        inv *= D[j];
      }
      acc[0] = fmaf(vc, inv, acc[0]);
    } else {
      // ---- slow path: near poles, direct per-tap eval (rare) ----
      #pragma unroll
      for (int j = 0; j < BG; ++j){
        const float xj = x0 + (float)j;
        if (xj == 0.0f) { hitv = v; hitj = j; }
        else {
          const float trj = xj * INV2K;
          const float cj  = __builtin_amdgcn_cosf(trj);
          const float sj  = __builtin_amdgcn_sinf(trj);
          acc[j] = fmaf((0.03125f * v) * cj, __builtin_amdgcn_rcpf(sj), acc[j]);
        }
      }
    }
  }

  // sign (-1)^(s+1): s parity constant per thread (m stride 256 even)
  __shared__ float red[4][BG];
  const int lane = tid & 63, wv = tid >> 6;
  const int p0 = (TAP0 + b0 - m0) & 1;
  #pragma unroll
  for (int j = 0; j < BG; ++j){
    const float sg = ((p0 + j) & 1) ? 1.0f : -1.0f;  // s odd -> +1
    const float hv = (hitj == j) ? hitv : 0.0f;
    float val = sg * scaleF * acc[j] + hv;
    val = wave_reduce(val);
    if (lane == 0) red[wv][j] = val;
  }
  __syncthreads();
  if (tid < BG){
    const float s = red[0][tid] + red[1][tid] + red[2][tid] + red[3][tid];
    ws[(((size_t)line * NBG + bg) * CH + chunk) * BG + tid] = s;
  }
}

// out[line] = sum_b filt[line][b] * tap[line][b]
__global__ __launch_bounds__(64) void weight_reduce(
    const float* __restrict__ ws, const float* __restrict__ filt,
    float* __restrict__ out)
{
  const int line = blockIdx.x;
  const int tid  = threadIdx.x;          // 0..63 == tap index b
  const int bg = tid >> 4, bb = tid & 15;
  float s = 0.f;
  #pragma unroll
  for (int c = 0; c < CH; ++c)
    s += ws[(((size_t)line * NBG + bg) * CH + c) * BG + bb];
  float val = s * filt[line * NBINS + tid];
  val = wave_reduce(val);
  if (tid == 0) out[line] = val;
}

extern "C" void kernel_launch(void* const* d_in, const int* in_sizes, int n_in,
                              void* d_out, int out_size, void* d_ws, size_t ws_size,
                              hipStream_t stream)
{
  const float* buffer = (const float*)d_in[0];
  const float* inputs = (const float*)d_in[1];
  const float* delays = (const float*)d_in[2];
  const float* filt   = (const float*)d_in[3];
  float* out = (float*)d_out;
  float* ws  = (float*)d_ws;

  frac_delay_taps<<<NLINES * NBG * CH, 256, 0, stream>>>(buffer, inputs, delays, ws);
  weight_reduce<<<NLINES, 64, 0, stream>>>(ws, filt, out);
}

// Round 3
// 32.661 us; speedup vs baseline: 7.7029x; 2.1024x over previous
//
#include <hip/hip_runtime.h>
#include <hip/hip_bf16.h>
#include <math.h>

#define NLINES 128
#define BUFLEN 48000
#define KLEN   96000
#define NBINS  64
#define TAP0   47935                 // BUFLEN - NBINS - 1
#define CH     16                    // m-chunks per line
#define MCH    (BUFLEN/CH)           // 3000
#define XCUT   224.0f                // fast path iff |xc| >= XCUT

#define INV2K  ((float)(0.5/(double)KLEN))                        // revolutions per sample
#define DLT_F  ((float)(3.14159265358979323846/(double)KLEN))     // pi/K radians

__device__ __forceinline__ float wave_reduce(float v){
  #pragma unroll
  for (int off = 32; off; off >>= 1) v += __shfl_down(v, off, 64);
  return v;
}

// h(x) = (-1)^(s+1) sin(pi d)/K * cot(pi(s-d)/K), s = TAP0+j-m, x = s-d.
// Fast path: Taylor moments of cot around group-center xc = TAP0+31.5-m-d:
//   cot(tc+Y) = w - uY + wuY^2 - u(1+3w^2)Y^3/3 + wu(2+3w^2)Y^4/3 - u(2+15w^2u)Y^5/15
// with w=cot(tc), u=1+w^2, Y=(j-31.5)*pi/K. Sign (-1)^(s+1) = (-1)^(j+m):
// (-1)^m folded into v, (-1)^j applied at reconstruction.
__global__ __launch_bounds__(256) void frac_delay_moments(
    const float* __restrict__ buffer, const float* __restrict__ inputs,
    const float* __restrict__ delays, const float* __restrict__ filt,
    float* __restrict__ ws)
{
  const int line  = blockIdx.x / CH;
  const int chunk = blockIdx.x % CH;
  const int tid   = threadIdx.x;

  const float d = delays[line];
  // sin(pi*d): d = r+f, |f|<=0.5 -> (-1)^r sin(pi f)
  const float r = rintf(d);
  const float f = d - r;
  float sp = __builtin_amdgcn_sinf(0.5f * f);
  if (((int)r) & 1) sp = -sp;
  const float scale0 = sp * (1.0f / (float)KLEN);

  const float inputv = inputs[line];
  const float* __restrict__ bufline  = buffer + (size_t)line * BUFLEN;
  const float* __restrict__ filtline = filt   + line * NBINS;

  const float cbase = (float)TAP0 + 31.5f - d;   // xc = cbase - m

  float A0=0.f, A1=0.f, A2=0.f, A3=0.f, A4=0.f, A5=0.f, sout=0.f;

  const int m0   = chunk * MCH + tid;
  const int mend = chunk * MCH + MCH;
  for (int m = m0; m < mend; m += 256){
    // rolled buffer: buf[m] = buffer[m+1] for m < L-1, inputs for m = L-1
    const float v  = (m < BUFLEN - 1) ? bufline[m + 1] : inputv;
    const float xc = cbase - (float)m;
    if (fabsf(xc) >= XCUT){
      const float vp = (m & 1) ? -v : v;             // fold (-1)^m
      const float tr = xc * INV2K;
      const float s  = __builtin_amdgcn_sinf(tr);    // sin(pi*xc/K)
      const float c  = __builtin_amdgcn_cosf(tr);
      const float w  = c * __builtin_amdgcn_rcpf(s);
      const float w2 = w * w;
      const float u  = w2 + 1.0f;
      const float vw = vp * w;
      const float vu = vp * u;
      A0 += vw;
      A1 += vu;
      const float t2 = vu * w;
      A2 += t2;
      const float e3 = fmaf(3.0f, w2, 1.0f);         // 1+3w^2
      A3 = fmaf(vu, e3, A3);
      A4 = fmaf(t2, e3 + 1.0f, A4);                  // vu*w*(2+3w^2)
      const float w2u = w2 * u;
      A5 = fmaf(vu, fmaf(15.0f, w2u, 2.0f), A5);     // vu*(2+15w^2u)
    } else {
      // slow path: near poles — exact per tap, filter folded in directly
      for (int j = 0; j < NBINS; ++j){
        const float xj = (float)(TAP0 + j - m) - d;  // exact small values
        float term;
        if (xj == 0.0f) term = v;                    // h(0) = 1
        else {
          const float trj = xj * INV2K;
          const float cj  = __builtin_amdgcn_cosf(trj);
          const float sj  = __builtin_amdgcn_sinf(trj);
          const float sg  = ((j + m) & 1) ? -1.0f : 1.0f;
          term = v * sg * scale0 * cj * __builtin_amdgcn_rcpf(sj);
        }
        sout = fmaf(term, filtline[j], sout);
      }
    }
  }

  // block-reduce 7 scalars
  __shared__ float red[4][8];
  const int lane = tid & 63, wv = tid >> 6;
  float vals[7] = {A0, A1, A2, A3, A4, A5, sout};
  #pragma unroll
  for (int k = 0; k < 7; ++k){
    float x = wave_reduce(vals[k]);
    if (lane == 0) red[wv][k] = x;
  }
  __syncthreads();
  if (tid < 7){
    const float s = red[0][tid] + red[1][tid] + red[2][tid] + red[3][tid];
    ws[(size_t)(line * CH + chunk) * 8 + tid] = s;
  }
}

// Reconstruct 64 taps from summed moments, fold reflection filters.
__global__ __launch_bounds__(64) void frac_delay_out(
    const float* __restrict__ ws, const float* __restrict__ delays,
    const float* __restrict__ filt, float* __restrict__ out)
{
  const int line = blockIdx.x;
  const int tid  = threadIdx.x;                    // tap index j
  __shared__ float mom[8];
  if (tid < 7){
    float s = 0.f;
    #pragma unroll
    for (int c = 0; c < CH; ++c) s += ws[(size_t)(line * CH + c) * 8 + tid];
    mom[tid] = s;
  }
  __syncthreads();

  const float d = delays[line];
  const float r = rintf(d);
  const float f = d - r;
  float sp = __builtin_amdgcn_sinf(0.5f * f);
  if (((int)r) & 1) sp = -sp;
  const float scale0 = sp * (1.0f / (float)KLEN);

  const float Y = ((float)tid - 31.5f) * DLT_F;
  float p =            -mom[5] * (1.0f/15.0f);
  p = fmaf(p, Y,        mom[4] * (1.0f/3.0f));
  p = fmaf(p, Y,       -mom[3] * (1.0f/3.0f));
  p = fmaf(p, Y,        mom[2]);
  p = fmaf(p, Y,       -mom[1]);
  p = fmaf(p, Y,        mom[0]);
  const float sg = (tid & 1) ? -1.0f : 1.0f;       // (-1)^j
  float val = sg * scale0 * p * filt[line * NBINS + tid];
  val = wave_reduce(val);
  if (tid == 0) out[line] = val + mom[6];
}

extern "C" void kernel_launch(void* const* d_in, const int* in_sizes, int n_in,
                              void* d_out, int out_size, void* d_ws, size_t ws_size,
                              hipStream_t stream)
{
  const float* buffer = (const float*)d_in[0];
  const float* inputs = (const float*)d_in[1];
  const float* delays = (const float*)d_in[2];
  const float* filt   = (const float*)d_in[3];
  float* out = (float*)d_out;
  float* ws  = (float*)d_ws;

  frac_delay_moments<<<NLINES * CH, 256, 0, stream>>>(buffer, inputs, delays, filt, ws);
  frac_delay_out<<<NLINES, 64, 0, stream>>>(ws, delays, filt, out);
}

// Round 4
// 18.125 us; speedup vs baseline: 13.8806x; 1.8020x over previous
//
#include <hip/hip_runtime.h>
#include <hip/hip_bf16.h>
#include <math.h>

#define NLINES 128
#define BUFLEN 48000
#define KLEN   96000
#define NBINS  64
#define TAP1   47936              // tap base in p-space (p = m+1, aligned buffer)
#define PSLOW  47616              // tail region start (exact path)
#define NQ     (PSLOW/4)          // 11904 quads per line
#define CH     8                  // chunks per line (kernel 1)
#define QCH    (NQ/CH)            // 1488 quads per chunk
#define TG     16                 // tail p-groups = waves in kernel 2

#define INV2K  5.2083333333333333e-06f  // 1/(2K): revolutions per sample
#define DLT_F  3.2724923474893679e-05f  // pi/K rad
#define TA_F   4.9087385252705e-05f     // tan(1.5*pi/K)
#define TB_F   1.6362461737446e-05f     // tan(0.5*pi/K)

__device__ __forceinline__ float wave_reduce(float v){
  #pragma unroll
  for (int off = 32; off; off >>= 1) v += __shfl_down(v, off, 64);
  return v;
}

__device__ __forceinline__ float sin_pi_d(float d){
  // sin(pi*d), range-split: d = r+f, |f|<=0.5 -> (-1)^r sin(pi f)
  const float r = rintf(d);
  float sp = __builtin_amdgcn_sinf(0.5f * (d - r));
  if (((int)r) & 1) sp = -sp;
  return sp;
}

// tap_j = sum_p v_p * h(x), x = (TAP1+j-p)-d, h = (-1)^(s+1) sin(pi d)/K cot(pi x/K)
// Kernel 1: p in [0,PSLOW) is guaranteed |x_center| >= 320 -> quartic Taylor
// moments of cot around the 64-tap center; sin/cos/rcp shared per float4 quad
// via cot(t+b) = (c - s tan b)/(s + c tan b), 4-way batch inversion.
__global__ __launch_bounds__(256) void frac_delay_moments(
    const float* __restrict__ buffer, const float* __restrict__ delays,
    float* __restrict__ ws)
{
  const int line  = blockIdx.x / CH;
  const int chunk = blockIdx.x % CH;
  const int tid   = threadIdx.x;

  const float d  = delays[line];
  const float Cq = 47966.0f - d;   // x at quad center (i=1.5) = Cq - P
  const float* __restrict__ bufline = buffer + (size_t)line * BUFLEN;

  float A0=0.f, A1=0.f, A2=0.f, A3=0.f, A4=0.f;

  const int qe = chunk * QCH + QCH;
  for (int q = chunk * QCH + tid; q < qe; q += 256){
    const int P = q << 2;
    float4 v = *reinterpret_cast<const float4*>(bufline + P);
    if (P == 0) v.x = 0.f;                 // p=0 excluded by the roll
    const float tr = (Cq - (float)P) * INV2K;
    const float s  = __builtin_amdgcn_sinf(tr);
    const float c  = __builtin_amdgcn_cosf(tr);
    // element i: b = (1.5-i)*dlt;  w_i = (c - s*tan b)/(s + c*tan b)
    const float D0 = fmaf(c,  TA_F, s), N0 = fmaf(s, -TA_F, c);
    const float D1 = fmaf(c,  TB_F, s), N1 = fmaf(s, -TB_F, c);
    const float D2 = fmaf(c, -TB_F, s), N2 = fmaf(s,  TB_F, c);
    const float D3 = fmaf(c, -TA_F, s), N3 = fmaf(s,  TA_F, c);
    const float P2 = D0*D1, P3 = P2*D2, P4 = P3*D3;
    const float inv = __builtin_amdgcn_rcpf(P4);
    const float I3 = inv*P3;
    const float r1 = inv*D3;
    const float I2 = r1*P2;
    const float r2 = r1*D2;
    const float I1 = r2*D0, I0 = r2*D1;
    const float w0 = N0*I0, w1 = N1*I1, w2q = N2*I2, w3 = N3*I3;

    // vp = (-1)^p v (P%4==0 -> pattern +,-,+,-); negs fold into fma operands
    #define MOMUP(W, VP) { \
      const float w2 = (W)*(W); \
      const float u  = w2 + 1.0f; \
      A0 = fmaf((VP), (W), A0); \
      const float vu = (VP)*u; \
      A1 += vu; \
      const float t2 = vu*(W); \
      A2 += t2; \
      const float e3 = fmaf(3.0f, w2, 1.0f); \
      A3 = fmaf(vu, e3, A3); \
      A4 = fmaf(t2, e3 + 1.0f, A4); }
    MOMUP(w0,  v.x)
    MOMUP(w1, -v.y)
    MOMUP(w2q, v.z)
    MOMUP(w3, -v.w)
    #undef MOMUP
  }

  __shared__ float red[4][8];
  const int lane = tid & 63, wv = tid >> 6;
  float vals[5] = {A0, A1, A2, A3, A4};
  #pragma unroll
  for (int k = 0; k < 5; ++k){
    float x = wave_reduce(vals[k]);
    if (lane == 0) red[wv][k] = x;
  }
  __syncthreads();
  if (tid < 5){
    const float s = red[0][tid] + red[1][tid] + red[2][tid] + red[3][tid];
    ws[(size_t)(line * CH + chunk) * 8 + tid] = s;
  }
}

// Kernel 2: exact tail (p in [PSLOW, BUFLEN] incl. input sample) + moment
// reconstruction + reflection-filter dot product -> out[line].
__global__ __launch_bounds__(1024) void frac_delay_tail(
    const float* __restrict__ buffer, const float* __restrict__ inputs,
    const float* __restrict__ delays, const float* __restrict__ filt,
    const float* __restrict__ ws, float* __restrict__ out)
{
  const int line = blockIdx.x;
  const int tid  = threadIdx.x;
  const int j = tid & 63, g = tid >> 6;        // tap, p-group(=wave)

  __shared__ float mom[8];
  __shared__ float red[TG][NBINS];
  if (tid < 5){
    float s = 0.f;
    #pragma unroll
    for (int c = 0; c < CH; ++c) s += ws[(size_t)(line * CH + c) * 8 + tid];
    mom[tid] = s;
  }

  const float d = delays[line];
  const float scale0 = sin_pi_d(d) * (1.0f / (float)KLEN);
  const float* __restrict__ bufline = buffer + (size_t)line * BUFLEN;

  float tj = 0.f;
  const int jj = TAP1 + j;
  for (int p = PSLOW + g; p < BUFLEN; p += TG){
    const float v = bufline[p];                // wave-uniform p: broadcast
    const float x = (float)(jj - p) - d;
    float term;
    if (x == 0.0f) term = v;                   // exact integer-delay hit
    else {
      const float tr = x * INV2K;
      const float ct = __builtin_amdgcn_cosf(tr) *
                       __builtin_amdgcn_rcpf(__builtin_amdgcn_sinf(tr));
      const float sg = ((j + p) & 1) ? 1.0f : -1.0f;   // (-1)^(1+j+p)
      term = sg * scale0 * v * ct;
    }
    tj += term;
  }
  if (g == 0){                                 // p = BUFLEN: the new input sample
    const float v = inputs[line];
    const int   p = BUFLEN;
    const float x = (float)(jj - p) - d;       // in [-96,-1], never 0
    const float tr = x * INV2K;
    const float ct = __builtin_amdgcn_cosf(tr) *
                     __builtin_amdgcn_rcpf(__builtin_amdgcn_sinf(tr));
    const float sg = ((j + p) & 1) ? 1.0f : -1.0f;
    tj += sg * scale0 * v * ct;
  }
  red[g][j] = tj;
  __syncthreads();

  if (tid < 64){
    float tail = 0.f;
    #pragma unroll
    for (int gg = 0; gg < TG; ++gg) tail += red[gg][tid];
    // cot series: w - uY + wuY^2 - u(1+3w^2)Y^3/3 + wu(2+3w^2)Y^4/3
    const float Y = ((float)tid - 31.5f) * DLT_F;
    float h =            mom[4] * (1.0f/3.0f);
    h = fmaf(h, Y,      -mom[3] * (1.0f/3.0f));
    h = fmaf(h, Y,       mom[2]);
    h = fmaf(h, Y,      -mom[1]);
    h = fmaf(h, Y,       mom[0]);
    const float sg = (tid & 1) ? 1.0f : -1.0f;         // (-1)^(j+1)
    const float tap = fmaf(sg * scale0, h, tail);
    float val = tap * filt[line * NBINS + tid];
    val = wave_reduce(val);
    if (tid == 0) out[line] = val;
  }
}

extern "C" void kernel_launch(void* const* d_in, const int* in_sizes, int n_in,
                              void* d_out, int out_size, void* d_ws, size_t ws_size,
                              hipStream_t stream)
{
  const float* buffer = (const float*)d_in[0];
  const float* inputs = (const float*)d_in[1];
  const float* delays = (const float*)d_in[2];
  const float* filt   = (const float*)d_in[3];
  float* out = (float*)d_out;
  float* ws  = (float*)d_ws;

  frac_delay_moments<<<NLINES * CH, 256, 0, stream>>>(buffer, delays, ws);
  frac_delay_tail<<<NLINES, 1024, 0, stream>>>(buffer, inputs, delays, filt, ws, out);
}